// Round 10
// baseline (84.056 us; speedup 1.0000x reference)
//
#include <hip/hip_runtime.h>
#include <math.h>

namespace {

constexpr int NUM_NEG   = 8;
constexpr int BROWS     = 262144;
constexpr int NUM_ITEMS_C = 20000;
constexpr int M_IMP_C   = 2000;
constexpr float MARGIN1 = 0.1f;
constexpr float MARGIN2 = 0.1f;
constexpr float TAU     = 0.2f;
constexpr float EPS1    = 1e-7f;
constexpr float MAXNORM = 1.0f - 1e-5f;

// phase-serial fusion: every block does [cls -> cl -> rank]
constexpr int NBLK   = 4096;
constexpr int NWAVES = NBLK * 4;   // 16384

__device__ __forceinline__ float wredsum(float v) {
    v += __shfl_xor(v, 1);  v += __shfl_xor(v, 2);  v += __shfl_xor(v, 4);
    v += __shfl_xor(v, 8);  v += __shfl_xor(v, 16); v += __shfl_xor(v, 32);
    return v;
}
__device__ __forceinline__ float wredmax(float v) {
    v = fmaxf(v, __shfl_xor(v, 1));  v = fmaxf(v, __shfl_xor(v, 2));
    v = fmaxf(v, __shfl_xor(v, 4));  v = fmaxf(v, __shfl_xor(v, 8));
    v = fmaxf(v, __shfl_xor(v, 16)); v = fmaxf(v, __shfl_xor(v, 32));
    return v;
}
__device__ __forceinline__ float bcast(float v, int l) {
    return __int_as_float(__builtin_amdgcn_readlane(__float_as_int(v), l));
}
__device__ __forceinline__ float fsq(float x)  { return __builtin_amdgcn_sqrtf(x); }
__device__ __forceinline__ float frc(float x)  { return __builtin_amdgcn_rcpf(x); }
__device__ __forceinline__ float artanh_fast(float n) {
    n = fminf(n, MAXNORM);
    return 0.5f * __logf((1.f + n) * frc(1.f - n));
}
__device__ __forceinline__ float acosh_fast(float z) {
    z = fmaxf(z, 1.0f + EPS1);
    return __logf(z + fsq(fmaf(z, z, -1.0f)));
}
__device__ __forceinline__ float tanh_fast(float x) {
    const float t = __expf(2.f * x);
    return (t - 1.f) * frc(t + 1.f);
}
__device__ __forceinline__ float dot4(const float4& a, const float4& b) {
    return (a.x * b.x + a.y * b.y) + (a.z * b.z + a.w * b.w);
}

__global__ __launch_bounds__(256) void fused_kernel(
        const float* __restrict__ emb,  const int* __restrict__ tri,
        const float* __restrict__ vtg,  const float* __restrict__ etag,
        const float* __restrict__ linw, const float* __restrict__ linb,
        const float* __restrict__ tw,   const int* __restrict__ labels,
        const int* __restrict__ imp,    float* __restrict__ part) {
    __shared__ float SA[64 * 65];   // W^T -> BT -> TT (pitch 65)
    __shared__ float s64[64];
    __shared__ float red4[4];
    const int tid  = threadIdx.x;
    const int lane = tid & 63, wid = tid >> 6;
    const int b    = blockIdx.x;
    const int gw   = b * 4 + wid;          // global wave id, 0..16383
    float wacc = 0.f;

    // ================= cls phase: <=2 items per wave, batched ==============
    for (int i = tid; i < 4096; i += 256) {
        const int r = i >> 6, d = i & 63;
        SA[d * 65 + r] = linw[i];          // W transposed, pitch 65
    }
    __syncthreads();
    const float bias = linb[lane];
    const float y2b  = wredsum(bias * bias);
    const int i0 = gw, i1 = gw + NWAVES;   // i0 < 16384 < 20000 always valid
    const bool v1 = (i1 < NUM_ITEMS_C);

    float xv0 = vtg[(long)i0 * 64 + lane];
    float xv1 = v1 ? vtg[(long)i1 * 64 + lane] : 0.f;

    auto prep = [&](float& x) -> float {   // ball_projx; returns xn
        float n2 = wredsum(x * x);
        float n  = fsq(fmaxf(n2, 1e-15f));
        if (n > MAXNORM) {                 // wave-uniform
            x *= MAXNORM * frc(n);
            n2 = wredsum(x * x);
            n  = fsq(fmaxf(n2, 1e-15f));
        }
        return n;
    };
    const float xn0 = prep(xv0);
    const float xn1 = prep(xv1);

    // batched mobius_matvec: share the W ds_read across both items
    float ma0 = 0.f, ma1 = 0.f, mb0 = 0.f, mb1 = 0.f;
    #pragma unroll
    for (int d = 0; d < 64; d += 2) {
        const float w0 = SA[(d)     * 65 + lane];
        const float w1 = SA[(d + 1) * 65 + lane];
        ma0 = fmaf(bcast(xv0, d), w0, ma0);  ma1 = fmaf(bcast(xv0, d + 1), w1, ma1);
        mb0 = fmaf(bcast(xv1, d), w0, mb0);  mb1 = fmaf(bcast(xv1, d + 1), w1, mb1);
    }
    auto tail = [&](float mx, float xn) -> float {  // -> log-mapped a (lane d)
        const float mn  = fsq(fmaxf(wredsum(mx * mx), 1e-15f));
        const float g   = tanh_fast(mn * frc(xn) * artanh_fast(xn));
        const float h1  = g * frc(mn) * mx;
        const float x2h = wredsum(h1 * h1);
        const float xy  = wredsum(h1 * bias);
        const float A   = 1.f + 2.f * xy + y2b;
        const float Bc  = 1.f - x2h;
        const float den = fmaxf(1.f + 2.f * xy + x2h * y2b, 1e-15f);
        float hh = (A * h1 + Bc * bias) * frc(den);
        float hn = fsq(fmaxf(wredsum(hh * hh), 1e-15f));
        if (hn > MAXNORM) {                // ball_projx (wave-uniform)
            hh *= MAXNORM * frc(hn);
            hn = fsq(fmaxf(wredsum(hh * hh), 1e-15f));
        }
        return artanh_fast(hn) * frc(hn) * hh;     // ball_logmap0
    };
    const float av0 = tail(ma0 + ma1, xn0);
    const float av1 = tail(mb0 + mb1, xn1);
    __syncthreads();
    // rebuild LDS: BT = logmap0(emb_tag)^T, s64 = ||bt||^2
    {
        const int j = tid >> 2, p = tid & 3;
        float e[16]; float s2 = 0.f;
        #pragma unroll
        for (int m = 0; m < 16; ++m) { e[m] = etag[j * 64 + p * 16 + m]; s2 += e[m] * e[m]; }
        s2 += __shfl_xor(s2, 1); s2 += __shfl_xor(s2, 2);
        const float n  = fsq(fmaxf(s2, 1e-15f));
        const float sc = artanh_fast(n) * frc(n);
        #pragma unroll
        for (int m = 0; m < 16; ++m) SA[(p * 16 + m) * 65 + j] = sc * e[m];
        if (p == 0) s64[j] = sc * sc * s2;
    }
    __syncthreads();
    const float twl = tw[lane];
    const float b2l = s64[lane];
    // batched tag-distance dot: share the BT ds_read across both items
    float da0 = 0.f, da1 = 0.f, db0 = 0.f, db1 = 0.f;
    #pragma unroll
    for (int d = 0; d < 64; d += 2) {
        const float w0 = SA[(d)     * 65 + lane];
        const float w1 = SA[(d + 1) * 65 + lane];
        da0 = fmaf(bcast(av0, d), w0, da0);  da1 = fmaf(bcast(av0, d + 1), w1, da1);
        db0 = fmaf(bcast(av1, d), w0, db0);  db1 = fmaf(bcast(av1, d + 1), w1, db1);
    }
    auto hinge = [&](float a, float dot, int i) -> float {
        const float a2v  = wredsum(a * a);
        const float dist = fsq(fmaxf(a2v + b2l - 2.f * dot, 1e-12f));
        const float logp = __logf(dist) - twl;
        float s0 = 0.f, s1 = 0.f, s2 = 0.f, s3 = 0.f;
        #pragma unroll
        for (int k = 0; k < 64; k += 4) {
            s0 += fmaxf(logp - bcast(logp, k)     + MARGIN1, 0.f);
            s1 += fmaxf(logp - bcast(logp, k + 1) + MARGIN1, 0.f);
            s2 += fmaxf(logp - bcast(logp, k + 2) + MARGIN1, 0.f);
            s3 += fmaxf(logp - bcast(logp, k + 3) + MARGIN1, 0.f);
        }
        const float hs = (s0 + s1) + (s2 + s3);
        const float c  = (labels[(long)i * 64 + lane] > 0) ? hs : 0.f;
        return wredsum(c);
    };
    wacc += hinge(av0, da0 + da1, i0);
    if (v1) wacc += hinge(av1, db0 + db1, i1);
    __syncthreads();

    // ================= cl phase (<=1 pair per wave) ========================
    {   // rebuild LDS: TT = emb_tag^T (raw), s64 = ||tag||^2
        const int j = tid >> 2, p = tid & 3;
        float s2 = 0.f;
        #pragma unroll
        for (int m = 0; m < 16; ++m) {
            const float e = etag[j * 64 + p * 16 + m];
            s2 += e * e;
            SA[(p * 16 + m) * 65 + j] = e;
        }
        s2 += __shfl_xor(s2, 1); s2 += __shfl_xor(s2, 2);
        if (p == 0) s64[j] = s2;
    }
    __syncthreads();
    if (gw < M_IMP_C) {
        const int ai = imp[gw * 2];
        const int bi = imp[gw * 2 + 1];
        const float y2l = s64[lane];
        const float x2  = s64[ai];
        float c0 = 0.f, c1 = 0.f, c2 = 0.f, c3 = 0.f;
        #pragma unroll
        for (int d = 0; d < 64; d += 4) {
            c0 = fmaf(SA[(d)     * 65 + ai], SA[(d)     * 65 + lane], c0);
            c1 = fmaf(SA[(d + 1) * 65 + ai], SA[(d + 1) * 65 + lane], c1);
            c2 = fmaf(SA[(d + 2) * 65 + ai], SA[(d + 2) * 65 + lane], c2);
            c3 = fmaf(SA[(d + 3) * 65 + ai], SA[(d + 3) * 65 + lane], c3);
        }
        const float c   = (c0 + c1) + (c2 + c3);
        const float A   = 1.f - 2.f * c + y2l;
        const float Bc  = 1.f - x2;
        const float nn  = A * A * x2 - 2.f * A * Bc * c + Bc * Bc * y2l;
        const float den = fmaxf(1.f - 2.f * c + x2 * y2l, 1e-15f);
        float n = fsq(fmaxf(nn * frc(den * den), 1e-15f));
        n = fminf(n, MAXNORM);
        const float dd = __logf((1.f + n) * frc(1.f - n));   // 2*artanh(n)
        float dist = dd * dd;
        if (lane == ai) dist = 0.f;        // self-distance: ref < 1e-9 -> masked
        const float logit = (dist > 1e-9f) ? (-dist * (1.f / TAU)) : -1e30f;
        const float dp = bcast(dist, bi);
        const float lp = bcast(logit, bi);
        const float m  = wredmax(logit);
        const float se = wredsum(__expf(logit - m)) + __expf(lp - m);
        wacc += m + __logf(se) + dp * (1.f / TAU);
    }

    // == rank: 8 lanes/row, 8 rows/wave, 2 row-sweeps software-pipelined ====
    {
        const int sub = lane & 7;          // dim octet: dims sub*8..sub*8+7
        const int rw  = lane >> 3;         // row within wave
        const int dof = sub * 8;
        const bool o0 = sub & 1;
        const bool o1 = (sub >> 1) & 1;
        const bool o2 = (sub >> 2) & 1;
        float racc = 0.f;

        // rows/sweep = NWAVES*8 = 131072; exactly 2 sweeps, both always valid
        const int  row0 = gw * 8 + rw;
        const int* t0 = tri + (long)row0 * 10;
        const int* t1 = t0 + (long)(NWAVES * 8) * 10;
        // --- all triples up front (10 int2 in flight) ---
        const int2 a01 = *reinterpret_cast<const int2*>(t0);
        const int2 a23 = *reinterpret_cast<const int2*>(t0 + 2);
        const int2 a45 = *reinterpret_cast<const int2*>(t0 + 4);
        const int2 a67 = *reinterpret_cast<const int2*>(t0 + 6);
        const int2 a89 = *reinterpret_cast<const int2*>(t0 + 8);
        const int2 b01 = *reinterpret_cast<const int2*>(t1);
        const int2 b23 = *reinterpret_cast<const int2*>(t1 + 2);
        const int2 b45 = *reinterpret_cast<const int2*>(t1 + 4);
        const int2 b67 = *reinterpret_cast<const int2*>(t1 + 6);
        const int2 b89 = *reinterpret_cast<const int2*>(t1 + 8);

        auto ldvec = [&](int idx, float4& lo, float4& hi) {
            const float* q = emb + (long)idx * 64 + dof;
            lo = *reinterpret_cast<const float4*>(q);
            hi = *reinterpret_cast<const float4*>(q + 4);
        };
        auto finish = [&](float e0, float e1, float e2, float e3,
                          float e4, float e5, float e6, float e7,
                          float ps, float alpha) {
            float s_;
            s_ = o0 ? e0 : e1; s_ = __shfl_xor(s_, 1); const float f0 = (o0 ? e1 : e0) + s_;
            s_ = o0 ? e2 : e3; s_ = __shfl_xor(s_, 1); const float f1 = (o0 ? e3 : e2) + s_;
            s_ = o0 ? e4 : e5; s_ = __shfl_xor(s_, 1); const float f2 = (o0 ? e5 : e4) + s_;
            s_ = o0 ? e6 : e7; s_ = __shfl_xor(s_, 1); const float f3 = (o0 ? e7 : e6) + s_;
            s_ = o1 ? f0 : f1; s_ = __shfl_xor(s_, 2); const float g0 = (o1 ? f1 : f0) + s_;
            s_ = o1 ? f2 : f3; s_ = __shfl_xor(s_, 2); const float g1 = (o1 ? f3 : f2) + s_;
            s_ = o2 ? g0 : g1; s_ = __shfl_xor(s_, 4); const float dn = (o2 ? g1 : g0) + s_;
            const float dneg = acosh_fast(-dn);
            float hk = fmaxf(ps - dneg * dneg + MARGIN2, 0.f);
            hk += __shfl_xor(hk, 1); hk += __shfl_xor(hk, 2); hk += __shfl_xor(hk, 4);
            if (sub == 0) racc += alpha * hk;   // alpha >= 0 factored out
        };

        // --- u/p vectors for BOTH sweeps ---
        float4 ua0, ub0, pa0, pb0, ua1, ub1, pa1, pb1;
        ldvec(a01.x, ua0, ub0);  ldvec(a01.y, pa0, pb0);
        ldvec(b01.x, ua1, ub1);  ldvec(b01.y, pa1, pb1);

        // --- sweep 0: all 16 neg loads first ---
        float4 na0,nb0, na1,nb1, na2,nb2, na3,nb3, na4,nb4, na5,nb5, na6,nb6, na7,nb7;
        ldvec(a23.x, na0, nb0);  ldvec(a23.y, na1, nb1);
        ldvec(a45.x, na2, nb2);  ldvec(a45.y, na3, nb3);
        ldvec(a67.x, na4, nb4);  ldvec(a67.y, na5, nb5);
        ldvec(a89.x, na6, nb6);  ldvec(a89.y, na7, nb7);

        const float u00 = ua0.x;            // dim0 (meaningful on sub==0)
        if (sub == 0) ua0.x = -ua0.x;       // fold lorentz sign into u
        float dp0 = dot4(ua0, pa0) + dot4(ub0, pb0);
        dp0 += __shfl_xor(dp0, 1); dp0 += __shfl_xor(dp0, 2); dp0 += __shfl_xor(dp0, 4);
        const float dpos0  = acosh_fast(-dp0);
        const float ps0    = dpos0 * dpos0;
        const float alpha0 = acosh_fast(u00);
        const float e0 = dot4(ua0, na0) + dot4(ub0, nb0);
        const float e1 = dot4(ua0, na1) + dot4(ub0, nb1);
        const float e2 = dot4(ua0, na2) + dot4(ub0, nb2);
        const float e3 = dot4(ua0, na3) + dot4(ub0, nb3);
        const float e4 = dot4(ua0, na4) + dot4(ub0, nb4);
        const float e5 = dot4(ua0, na5) + dot4(ub0, nb5);
        const float e6 = dot4(ua0, na6) + dot4(ub0, nb6);
        const float e7 = dot4(ua0, na7) + dot4(ub0, nb7);

        // --- sweep 1: issue its 16 neg loads while sweep-0 finishes ---
        float4 ma0v,mb0v, ma1v,mb1v, ma2v,mb2v, ma3v,mb3v,
               ma4v,mb4v, ma5v,mb5v, ma6v,mb6v, ma7v,mb7v;
        ldvec(b23.x, ma0v, mb0v);  ldvec(b23.y, ma1v, mb1v);
        ldvec(b45.x, ma2v, mb2v);  ldvec(b45.y, ma3v, mb3v);
        ldvec(b67.x, ma4v, mb4v);  ldvec(b67.y, ma5v, mb5v);
        ldvec(b89.x, ma6v, mb6v);  ldvec(b89.y, ma7v, mb7v);

        finish(e0, e1, e2, e3, e4, e5, e6, e7, ps0, alpha0);

        const float u01 = ua1.x;
        if (sub == 0) ua1.x = -ua1.x;
        float dp1 = dot4(ua1, pa1) + dot4(ub1, pb1);
        dp1 += __shfl_xor(dp1, 1); dp1 += __shfl_xor(dp1, 2); dp1 += __shfl_xor(dp1, 4);
        const float dpos1  = acosh_fast(-dp1);
        const float ps1    = dpos1 * dpos1;
        const float alpha1 = acosh_fast(u01);
        const float h0 = dot4(ua1, ma0v) + dot4(ub1, mb0v);
        const float h1 = dot4(ua1, ma1v) + dot4(ub1, mb1v);
        const float h2 = dot4(ua1, ma2v) + dot4(ub1, mb2v);
        const float h3 = dot4(ua1, ma3v) + dot4(ub1, mb3v);
        const float h4 = dot4(ua1, ma4v) + dot4(ub1, mb4v);
        const float h5 = dot4(ua1, ma5v) + dot4(ub1, mb5v);
        const float h6 = dot4(ua1, ma6v) + dot4(ub1, mb6v);
        const float h7 = dot4(ua1, ma7v) + dot4(ub1, mb7v);
        finish(h0, h1, h2, h3, h4, h5, h6, h7, ps1, alpha1);

        wacc += wredsum(racc);
    }

    if (lane == 0) red4[wid] = wacc;
    __syncthreads();
    if (tid == 0) part[b] = red4[0] + red4[1] + red4[2] + red4[3];
}

__global__ __launch_bounds__(256) void final_reduce(
        const float* __restrict__ parts, int n, float* __restrict__ out) {
    __shared__ double red[256];
    double s = 0.0;
    for (int i = threadIdx.x; i < n; i += 256) s += (double)parts[i];
    red[threadIdx.x] = s;
    __syncthreads();
    for (int off = 128; off > 0; off >>= 1) {
        if (threadIdx.x < off) red[threadIdx.x] += red[threadIdx.x + off];
        __syncthreads();
    }
    if (threadIdx.x == 0) out[0] = (float)red[0];
}

} // namespace

extern "C" void kernel_launch(void* const* d_in, const int* in_sizes, int n_in,
                              void* d_out, int out_size, void* d_ws, size_t ws_size,
                              hipStream_t stream) {
    const float* emb    = (const float*)d_in[0];
    const float* vtg    = (const float*)d_in[1];
    const float* etag   = (const float*)d_in[2];
    const float* linw   = (const float*)d_in[3];
    const float* linb   = (const float*)d_in[4];
    const float* tw     = (const float*)d_in[5];
    const int*   tri    = (const int*)d_in[6];
    const int*   labels = (const int*)d_in[7];
    const int*   imp    = (const int*)d_in[8];
    float* parts = (float*)d_ws;

    fused_kernel<<<NBLK, 256, 0, stream>>>(emb, tri, vtg, etag, linw, linb,
                                           tw, labels, imp, parts);
    final_reduce<<<1, 256, 0, stream>>>(parts, NBLK, (float*)d_out);
}